// Round 10
// baseline (81.117 us; speedup 1.0000x reference)
//
#include <hip/hip_runtime.h>
#include <math.h>

#define A_N 5
#define NC 20
#define FD 38
#define SD (FD*FD)        // 1444
#define BD 32
#define OD 50
#define SA (SD*A_N)       // 7220
#define GXP 29            // pos blocks per batch (29*256 = 7424 >= 7220)
#define SLOTB 30          // 29 pos partial slots + 1 resp slot per batch
#define NSLOT (BD * SLOTB)  // 960
#define IGN_T 0.6f
#define OBJ_S 5.0f

__device__ __forceinline__ float sigm(float x) { return 1.0f / (1.0f + __expf(-x)); }

// ---------------- Kernel 1: everything --------------------------------------
// grid (GXP+1, BD). blockIdx.x < GXP: noobj/ignore pass, 1 position/thread
// (960 blocks -> ~3.75 waves/SIMD). The loop only THRESHOLD-TESTS IoU:
//   m >= 0.6  <=>  exists o: 1.6*in >= 0.6*(ar+dn)  <=>  dmax >= 0
// (dmax = max_o of 1.6*in - 0.6*ar - 0.6*dn; sign also gives m > 0.6).
// blockIdx.x == GXP: 32 light blocks computing responsible-object terms.
// Speculative n_pos split: base always counts; corr counts iff n_pos==0.
__global__ __launch_bounds__(256) void k_main(
    const float* __restrict__ outputs, const float* __restrict__ targets,
    const float* __restrict__ anchors,
    float* __restrict__ pbase, float* __restrict__ pcorr, int* __restrict__ pflag)
{
    __shared__ float4 g_box[OD];              // (tlx, tly, brx, bry)
    __shared__ float  g_e[OD];                // 0.6 * (area + 1e-12)
    __shared__ float  s_anc[2 * A_N];
    __shared__ int    s_cnt, s_any;
    __shared__ int    s_key[OD];
    __shared__ float  wb[4], wc[4];

    const int b = blockIdx.y;
    const int tid = threadIdx.x;
    if (tid == 0) s_any = 0;
    if (tid < 2 * A_N) s_anc[tid] = anchors[tid];

    if (blockIdx.x == GXP) {
        // ---- responsible-object block (1 per batch) ----
        if (tid == 0) s_cnt = 0;
        __syncthreads();
        float gx = 0, gy = 0, gw = 0, gh = 0;
        int ct = 0, key = -1;
        if (tid < OD) {
            const float* t = targets + (b * OD + tid) * 5;
            float tx = t[0], ty = t[1], tw = t[2], th = t[3], tc = t[4];
            if (tx + ty + tw + th + tc > 0.0f) {
                gx = tx * FD; gy = ty * FD; gw = tw * FD; gh = th * FD;
                float gtlx = gx - gw*0.5f, gtly = gy - gh*0.5f;
                float gbrx = gx + gw*0.5f, gbry = gy + gh*0.5f;
                int k = atomicAdd(&s_cnt, 1);
                g_box[k] = make_float4(gtlx, gtly, gbrx, gbry);
                g_e[k] = gw * gh + 1e-12f;     // plain den here (resp path)
                int cx = (int)floorf(gtlx), cy = (int)floorf(gtly);
                int cell = min(max(cy * FD + cx, 0), SD - 1);
                int ci = cell / FD, cj = cell - ci * FD;
                float acx = (float)cj + 0.5f, acy = (float)ci + 0.5f;
                float areaB = gw * gh;
                float best = -1.0f; int bi = 0;
                for (int a = 0; a < A_N; ++a) {
                    float aw = s_anc[2*a] * FD, ah = s_anc[2*a+1] * FD;
                    float w = fmaxf(fminf(acx + aw*0.5f, gbrx) - fmaxf(acx - aw*0.5f, gtlx), 0.0f);
                    float h = fmaxf(fminf(acy + ah*0.5f, gbry) - fmaxf(acy - ah*0.5f, gtly), 0.0f);
                    float inter = w * h;
                    float iou = inter / (aw*ah + areaB - inter + 1e-12f);
                    if (iou > best) { best = iou; bi = a; }
                }
                key = bi * SD + cell;
                ct = (int)tc;
            }
        }
        if (tid < OD) s_key[tid] = key;
        __syncthreads();
        const int cnt = s_cnt;

        float rbase = 0.0f, rcorr = 0.0f;
        if (tid < OD && key >= 0) {
            int win = -1;                      // last duplicate wins == numpy
            #pragma unroll 10
            for (int o = 0; o < OD; ++o) win = (s_key[o] == key) ? o : win;
            if (win == tid) {
                int a = key / SD, cell = key - a * SD;
                int ci = cell / FD, cj = cell - ci * FD;
                const float* ob = outputs + ((size_t)b * (A_N * 25) + a * 25) * SD + cell;
                float o0 = ob[0], o1 = ob[SD], o2 = ob[2*SD], o3 = ob[3*SD], o4 = ob[4*SD];
                float aw = s_anc[2*a] * FD, ah = s_anc[2*a+1] * FD;
                float px = sigm(o0) + (float)cj;
                float py = sigm(o1) + (float)ci;
                float ew = __expf(o2), eh = __expf(o3);
                float pw = ew * aw, ph = eh * ah;
                float tlx = px - pw*0.5f, tly = py - ph*0.5f;
                float brx = px + pw*0.5f, bry = py + ph*0.5f;
                float ar = pw * ph;
                float bn = 0.0f, bd = 1.0f;
                for (int o = 0; o < cnt; ++o) {
                    float4 bx = g_box[o];
                    float w = fmaxf(fminf(brx, bx.z) - fmaxf(tlx, bx.x), 0.0f);
                    float h = fmaxf(fminf(bry, bx.w) - fmaxf(tly, bx.y), 0.0f);
                    float in = w * h, de = ar + g_e[o] - in;
                    if (in * bd > bn * de) { bn = in; bd = de; }
                }
                float mi = bn / bd;
                float conf = sigm(o4);
                float d = conf - mi;                   // iou loss, mask=OBJ_SCALE
                rbase += OBJ_S * OBJ_S * d * d;
                float c2 = conf * conf;                // undo pos-block noobj term
                if (bn >= IGN_T * bd) rcorr -= c2;
                else                  rbase -= c2;
                // box loss: pd = [sigm, sigm, exp, exp] (NO anchor scale on pd)
                float dx = gx - ((float)cj + 0.5f);
                float dy = gy - ((float)ci + 0.5f);
                float e0 = sigm(o0) - dx;
                float e1 = sigm(o1) - dy;
                float e2 = ew - gw / aw;
                float e3 = eh - gh / ah;
                rbase += e0*e0 + e1*e1 + e2*e2 + e3*e3;
                // class loss: ce = -log_softmax(softmax(x))[ct], register-lean.
                // pmax == 1/esum algebraically (bit-identical).
                const float* cb = ob + 5 * SD;
                float xmax = -INFINITY;
                #pragma unroll
                for (int k = 0; k < NC; ++k) xmax = fmaxf(xmax, cb[k * SD]);
                float esum = 0.0f;
                #pragma unroll
                for (int k = 0; k < NC; ++k) esum += __expf(cb[k * SD] - xmax);
                float inv = 1.0f / esum;
                float pmax = inv;
                float pct = __expf(cb[ct * SD] - xmax) * inv;
                float e2s = 0.0f;
                #pragma unroll
                for (int k = 0; k < NC; ++k)
                    e2s += __expf(__expf(cb[k * SD] - xmax) * inv - pmax);
                rbase += -(pct - (pmax + __logf(e2s)));
            }
        }
        #pragma unroll
        for (int off = 32; off > 0; off >>= 1) {
            rbase += __shfl_down(rbase, off);
            rcorr += __shfl_down(rcorr, off);
        }
        int lane = tid & 63, w = tid >> 6;
        if (lane == 0) { wb[w] = rbase; wc[w] = rcorr; }
        __syncthreads();
        if (tid == 0) {
            int gid = b * SLOTB + GXP;
            pbase[gid] = wb[0] + wb[1] + wb[2] + wb[3];
            pcorr[gid] = wc[0] + wc[1] + wc[2] + wc[3];
            pflag[gid] = 0;
        }
        return;
    }

    // ---- position blocks: 1 position/thread, threshold-test loop ----
    const int idx = blockIdx.x * 256 + tid;
    const bool act = (idx < SA);
    const int a = idx / SD, s = idx - a * SD;
    const int i = s / FD, j = s - i * FD;
    const float* ob = outputs + ((size_t)b * (A_N * 25) + a * 25) * SD + s;
    float q0 = 0, q1 = 0, q2 = 0, q3 = 0, q4 = 0;
    if (act) { q0 = ob[0]; q1 = ob[SD]; q2 = ob[2*SD]; q3 = ob[3*SD]; q4 = ob[4*SD]; }

    // GT staging: wave 0, ballot-compaction (no LDS atomics)
    if (tid < 64) {
        bool v = false;
        float gtlx = 0, gtly = 0, gbrx = 0, gbry = 0, e = 0;
        if (tid < OD) {
            const float* t = targets + (b * OD + tid) * 5;
            float tx = t[0], ty = t[1], tw = t[2], th = t[3], tc = t[4];
            if (tx + ty + tw + th + tc > 0.0f) {
                v = true;
                float gx = tx * FD, gy = ty * FD, gw = tw * FD, gh = th * FD;
                gtlx = gx - gw*0.5f; gtly = gy - gh*0.5f;
                gbrx = gx + gw*0.5f; gbry = gy + gh*0.5f;
                e = IGN_T * (gw * gh + 1e-12f);        // 0.6*dn
            }
        }
        unsigned long long bal = __ballot(v);
        if (v) {
            int k = __popcll(bal & ((1ull << tid) - 1ull));
            g_box[k] = make_float4(gtlx, gtly, gbrx, gbry);
            g_e[k] = e;
        }
        if (tid == 0) s_cnt = __popcll(bal);
    }
    __syncthreads();
    const int cnt = s_cnt;

    float base = 0.0f, corr = 0.0f;
    bool hot = false;
    if (act) {
        float aw = s_anc[2*a] * FD, ah = s_anc[2*a+1] * FD;
        float px = sigm(q0) + (float)j;
        float py = sigm(q1) + (float)i;
        float pw = __expf(q2) * aw;
        float ph = __expf(q3) * ah;
        float tlx = px - pw*0.5f, tly = py - ph*0.5f;
        float brx = px + pw*0.5f, bry = py + ph*0.5f;
        float f6 = IGN_T * (pw * ph);                  // 0.6*ar

        float dmax = -1e30f;
        for (int o = 0; o < cnt; ++o) {
            float4 bx = g_box[o];
            float w = fmaxf(fminf(brx, bx.z) - fmaxf(tlx, bx.x), 0.0f);
            float h = fmaxf(fminf(bry, bx.w) - fmaxf(tly, bx.y), 0.0f);
            float in = w * h;
            float d = (1.0f + IGN_T) * in - g_e[o] - f6;   // sign(d) = sign(iou-0.6)
            dmax = fmaxf(dmax, d);
        }
        hot = (dmax > 0.0f);                           // m >  0.6 (n_pos)
        float c2 = sigm(q4); c2 *= c2;
        if (dmax >= 0.0f) corr += c2;                  // m >= 0.6
        else              base += c2;
    }

    unsigned long long bal = __ballot(hot);
    if ((tid & 63) == 0 && bal) atomicOr(&s_any, 1);

    #pragma unroll
    for (int off = 32; off > 0; off >>= 1) {
        base += __shfl_down(base, off);
        corr += __shfl_down(corr, off);
    }
    int lane = tid & 63, w = tid >> 6;
    if (lane == 0) { wb[w] = base; wc[w] = corr; }
    __syncthreads();
    if (tid == 0) {
        int gid = b * SLOTB + blockIdx.x;
        pbase[gid] = wb[0] + wb[1] + wb[2] + wb[3];
        pcorr[gid] = wc[0] + wc[1] + wc[2] + wc[3];
        pflag[gid] = s_any;
    }
}

// ---------------- Kernel 2: trivial combine ----------------------------------
__global__ __launch_bounds__(256) void k_fin(
    const float* __restrict__ pbase, const float* __restrict__ pcorr,
    const int* __restrict__ pflag, float* __restrict__ out)
{
    __shared__ int npos[BD];
    __shared__ float wsum[4];
    const int tid = threadIdx.x;
    if (tid < BD) {
        int f = 0;
        for (int x = 0; x < SLOTB; ++x) f |= pflag[tid * SLOTB + x];
        npos[tid] = f;
    }
    __syncthreads();
    float s = 0.0f;
    for (int g = tid; g < NSLOT; g += 256)
        s += pbase[g] + (npos[g / SLOTB] ? 0.0f : pcorr[g]);
    #pragma unroll
    for (int off = 32; off > 0; off >>= 1) s += __shfl_down(s, off);
    int lane = tid & 63, w = tid >> 6;
    if (lane == 0) wsum[w] = s;
    __syncthreads();
    if (tid == 0) out[0] = (wsum[0] + wsum[1] + wsum[2] + wsum[3]) * (1.0f / (float)BD);
}

extern "C" void kernel_launch(void* const* d_in, const int* in_sizes, int n_in,
                              void* d_out, int out_size, void* d_ws, size_t ws_size,
                              hipStream_t stream) {
    (void)in_sizes; (void)n_in; (void)out_size; (void)ws_size;
    const float* outputs = (const float*)d_in[0];
    const float* targets = (const float*)d_in[1];
    const float* anchors = (const float*)d_in[2];
    float* out = (float*)d_out;

    float* pbase = (float*)d_ws;
    float* pcorr = pbase + NSLOT;
    int*   pflag = (int*)(pcorr + NSLOT);

    k_main<<<dim3(GXP + 1, BD), 256, 0, stream>>>(outputs, targets, anchors,
                                                  pbase, pcorr, pflag);
    k_fin<<<dim3(1), 256, 0, stream>>>(pbase, pcorr, pflag, out);
}

// Round 11
// 76.608 us; speedup vs baseline: 1.0589x; 1.0589x over previous
//
#include <hip/hip_runtime.h>
#include <math.h>

#define A_N 5
#define NC 20
#define FD 38
#define SD (FD*FD)        // 1444
#define BD 32
#define OD 50
#define SA (SD*A_N)       // 7220
#define HALF (SA/2)       // 3610 — each pos-thread does p and p+HALF
#define GXP 15            // pos blocks per batch (15*256 = 3840 >= 3610)
#define SLOTB 16          // 15 pos partial slots + 1 resp slot per batch
#define NSLOT (BD * SLOTB)  // 512
#define IGN_T 0.6f
#define OBJ_S 5.0f

__device__ __forceinline__ float sigm(float x) { return 1.0f / (1.0f + __expf(-x)); }

// ---------------- Kernel 1: everything --------------------------------------
// grid (GXP+1, BD). blockIdx.x < GXP: noobj/ignore pass, 2 positions/thread
// (dual-strand ILP — best measured config, R8). The loop only THRESHOLD-TESTS
// IoU:  m >= 0.6  <=>  dmax >= 0  where dmax = max_o(1.6*in - 0.6*(ar+dn)).
// blockIdx.x == GXP: 32 light blocks computing responsible-object terms.
// Speculative n_pos split: base always counts; corr counts iff n_pos==0.
__global__ __launch_bounds__(256) void k_main(
    const float* __restrict__ outputs, const float* __restrict__ targets,
    const float* __restrict__ anchors,
    float* __restrict__ pbase, float* __restrict__ pcorr, int* __restrict__ pflag)
{
    __shared__ float4 g_box[OD];              // (tlx, tly, brx, bry)
    __shared__ float  g_e[OD];                // pos: 0.6*(area+1e-12); resp: area+1e-12
    __shared__ float  s_anc[2 * A_N];
    __shared__ int    s_cnt, s_any;
    __shared__ int    s_key[OD];
    __shared__ float  wb[4], wc[4];

    const int b = blockIdx.y;
    const int tid = threadIdx.x;
    if (tid == 0) s_any = 0;
    if (tid < 2 * A_N) s_anc[tid] = anchors[tid];

    if (blockIdx.x == GXP) {
        // ---- responsible-object block (1 per batch) ----
        if (tid == 0) s_cnt = 0;
        __syncthreads();
        float gx = 0, gy = 0, gw = 0, gh = 0;
        int ct = 0, key = -1;
        if (tid < OD) {
            const float* t = targets + (b * OD + tid) * 5;
            float tx = t[0], ty = t[1], tw = t[2], th = t[3], tc = t[4];
            if (tx + ty + tw + th + tc > 0.0f) {
                gx = tx * FD; gy = ty * FD; gw = tw * FD; gh = th * FD;
                float gtlx = gx - gw*0.5f, gtly = gy - gh*0.5f;
                float gbrx = gx + gw*0.5f, gbry = gy + gh*0.5f;
                int k = atomicAdd(&s_cnt, 1);
                g_box[k] = make_float4(gtlx, gtly, gbrx, gbry);
                g_e[k] = gw * gh + 1e-12f;     // plain den (resp path)
                int cx = (int)floorf(gtlx), cy = (int)floorf(gtly);
                int cell = min(max(cy * FD + cx, 0), SD - 1);
                int ci = cell / FD, cj = cell - ci * FD;
                float acx = (float)cj + 0.5f, acy = (float)ci + 0.5f;
                float areaB = gw * gh;
                float best = -1.0f; int bi = 0;
                for (int a = 0; a < A_N; ++a) {
                    float aw = s_anc[2*a] * FD, ah = s_anc[2*a+1] * FD;
                    float w = fmaxf(fminf(acx + aw*0.5f, gbrx) - fmaxf(acx - aw*0.5f, gtlx), 0.0f);
                    float h = fmaxf(fminf(acy + ah*0.5f, gbry) - fmaxf(acy - ah*0.5f, gtly), 0.0f);
                    float inter = w * h;
                    float iou = inter / (aw*ah + areaB - inter + 1e-12f);
                    if (iou > best) { best = iou; bi = a; }
                }
                key = bi * SD + cell;
                ct = (int)tc;
            }
        }
        if (tid < OD) s_key[tid] = key;
        __syncthreads();
        const int cnt = s_cnt;

        float rbase = 0.0f, rcorr = 0.0f;
        if (tid < OD && key >= 0) {
            int win = -1;                      // last duplicate wins == numpy
            #pragma unroll 10
            for (int o = 0; o < OD; ++o) win = (s_key[o] == key) ? o : win;
            if (win == tid) {
                int a = key / SD, cell = key - a * SD;
                int ci = cell / FD, cj = cell - ci * FD;
                const float* ob = outputs + ((size_t)b * (A_N * 25) + a * 25) * SD + cell;
                float o0 = ob[0], o1 = ob[SD], o2 = ob[2*SD], o3 = ob[3*SD], o4 = ob[4*SD];
                float aw = s_anc[2*a] * FD, ah = s_anc[2*a+1] * FD;
                float px = sigm(o0) + (float)cj;
                float py = sigm(o1) + (float)ci;
                float ew = __expf(o2), eh = __expf(o3);
                float pw = ew * aw, ph = eh * ah;
                float tlx = px - pw*0.5f, tly = py - ph*0.5f;
                float brx = px + pw*0.5f, bry = py + ph*0.5f;
                float ar = pw * ph;
                float bn = 0.0f, bd = 1.0f;
                for (int o = 0; o < cnt; ++o) {
                    float4 bx = g_box[o];
                    float w = fmaxf(fminf(brx, bx.z) - fmaxf(tlx, bx.x), 0.0f);
                    float h = fmaxf(fminf(bry, bx.w) - fmaxf(tly, bx.y), 0.0f);
                    float in = w * h, de = ar + g_e[o] - in;
                    if (in * bd > bn * de) { bn = in; bd = de; }
                }
                float mi = bn / bd;
                float conf = sigm(o4);
                float d = conf - mi;                   // iou loss, mask=OBJ_SCALE
                rbase += OBJ_S * OBJ_S * d * d;
                float c2 = conf * conf;                // undo pos-block noobj term
                if (bn >= IGN_T * bd) rcorr -= c2;
                else                  rbase -= c2;
                // box loss: pd = [sigm, sigm, exp, exp] (NO anchor scale on pd)
                float dx = gx - ((float)cj + 0.5f);
                float dy = gy - ((float)ci + 0.5f);
                float e0 = sigm(o0) - dx;
                float e1 = sigm(o1) - dy;
                float e2 = ew - gw / aw;
                float e3 = eh - gh / ah;
                rbase += e0*e0 + e1*e1 + e2*e2 + e3*e3;
                // class loss: ce = -log_softmax(softmax(x))[ct], register-lean.
                // pmax == 1/esum algebraically (bit-identical).
                const float* cb = ob + 5 * SD;
                float xmax = -INFINITY;
                #pragma unroll
                for (int k = 0; k < NC; ++k) xmax = fmaxf(xmax, cb[k * SD]);
                float esum = 0.0f;
                #pragma unroll
                for (int k = 0; k < NC; ++k) esum += __expf(cb[k * SD] - xmax);
                float inv = 1.0f / esum;
                float pmax = inv;
                float pct = __expf(cb[ct * SD] - xmax) * inv;
                float e2s = 0.0f;
                #pragma unroll
                for (int k = 0; k < NC; ++k)
                    e2s += __expf(__expf(cb[k * SD] - xmax) * inv - pmax);
                rbase += -(pct - (pmax + __logf(e2s)));
            }
        }
        #pragma unroll
        for (int off = 32; off > 0; off >>= 1) {
            rbase += __shfl_down(rbase, off);
            rcorr += __shfl_down(rcorr, off);
        }
        int lane = tid & 63, w = tid >> 6;
        if (lane == 0) { wb[w] = rbase; wc[w] = rcorr; }
        __syncthreads();
        if (tid == 0) {
            int gid = b * SLOTB + GXP;
            pbase[gid] = wb[0] + wb[1] + wb[2] + wb[3];
            pcorr[gid] = wc[0] + wc[1] + wc[2] + wc[3];
            pflag[gid] = 0;
        }
        return;
    }

    // ---- position blocks: dual-strand, threshold-test loop ----
    const int ix = blockIdx.x * 256 + tid;
    const bool act = (ix < HALF);
    const int p0 = ix, p1 = ix + HALF;
    int a0 = p0 / SD, r0 = p0 - a0 * SD;
    int a1 = p1 / SD, r1 = p1 - a1 * SD;
    int ii0 = r0 / FD, jj0 = r0 - ii0 * FD;
    int ii1 = r1 / FD, jj1 = r1 - ii1 * FD;
    const float* ob0 = outputs + ((size_t)b * (A_N * 25) + a0 * 25) * SD + r0;
    const float* ob1 = outputs + ((size_t)b * (A_N * 25) + a1 * 25) * SD + r1;
    float q00 = 0, q01 = 0, q02 = 0, q03 = 0, q04 = 0;
    float q10 = 0, q11 = 0, q12 = 0, q13 = 0, q14 = 0;
    if (act) {
        q00 = ob0[0]; q01 = ob0[SD]; q02 = ob0[2*SD]; q03 = ob0[3*SD]; q04 = ob0[4*SD];
        q10 = ob1[0]; q11 = ob1[SD]; q12 = ob1[2*SD]; q13 = ob1[3*SD]; q14 = ob1[4*SD];
    }

    // GT staging: wave 0, ballot-compaction (no LDS atomics)
    if (tid < 64) {
        bool v = false;
        float gtlx = 0, gtly = 0, gbrx = 0, gbry = 0, e = 0;
        if (tid < OD) {
            const float* t = targets + (b * OD + tid) * 5;
            float tx = t[0], ty = t[1], tw = t[2], th = t[3], tc = t[4];
            if (tx + ty + tw + th + tc > 0.0f) {
                v = true;
                float gx = tx * FD, gy = ty * FD, gw = tw * FD, gh = th * FD;
                gtlx = gx - gw*0.5f; gtly = gy - gh*0.5f;
                gbrx = gx + gw*0.5f; gbry = gy + gh*0.5f;
                e = IGN_T * (gw * gh + 1e-12f);        // 0.6*dn
            }
        }
        unsigned long long bal = __ballot(v);
        if (v) {
            int k = __popcll(bal & ((1ull << tid) - 1ull));
            g_box[k] = make_float4(gtlx, gtly, gbrx, gbry);
            g_e[k] = e;
        }
        if (tid == 0) s_cnt = __popcll(bal);
    }
    __syncthreads();
    const int cnt = s_cnt;

    float base = 0.0f, corr = 0.0f;
    bool hot = false;
    if (act) {
        float aw0 = s_anc[2*a0] * FD, ah0 = s_anc[2*a0+1] * FD;
        float aw1 = s_anc[2*a1] * FD, ah1 = s_anc[2*a1+1] * FD;
        float px0 = sigm(q00) + (float)jj0, py0 = sigm(q01) + (float)ii0;
        float px1 = sigm(q10) + (float)jj1, py1 = sigm(q11) + (float)ii1;
        float pw0 = __expf(q02) * aw0, ph0 = __expf(q03) * ah0;
        float pw1 = __expf(q12) * aw1, ph1 = __expf(q13) * ah1;
        float tlx0 = px0 - pw0*0.5f, tly0 = py0 - ph0*0.5f;
        float brx0 = px0 + pw0*0.5f, bry0 = py0 + ph0*0.5f;
        float tlx1 = px1 - pw1*0.5f, tly1 = py1 - ph1*0.5f;
        float brx1 = px1 + pw1*0.5f, bry1 = py1 + ph1*0.5f;
        float f60 = IGN_T * (pw0 * ph0);               // 0.6*ar0
        float f61 = IGN_T * (pw1 * ph1);               // 0.6*ar1

        float dm0 = -1e30f, dm1 = -1e30f;
        for (int o = 0; o < cnt; ++o) {
            float4 bx = g_box[o];
            float e = g_e[o];
            float w0 = fmaxf(fminf(brx0, bx.z) - fmaxf(tlx0, bx.x), 0.0f);
            float h0 = fmaxf(fminf(bry0, bx.w) - fmaxf(tly0, bx.y), 0.0f);
            dm0 = fmaxf(dm0, fmaf((1.0f + IGN_T), w0 * h0, -(e + f60)));
            float w1 = fmaxf(fminf(brx1, bx.z) - fmaxf(tlx1, bx.x), 0.0f);
            float h1 = fmaxf(fminf(bry1, bx.w) - fmaxf(tly1, bx.y), 0.0f);
            dm1 = fmaxf(dm1, fmaf((1.0f + IGN_T), w1 * h1, -(e + f61)));
        }
        hot = (dm0 > 0.0f) || (dm1 > 0.0f);            // m > 0.6 (n_pos)
        float c0 = sigm(q04); c0 *= c0;
        float c1 = sigm(q14); c1 *= c1;
        if (dm0 >= 0.0f) corr += c0; else base += c0;  // m >= 0.6
        if (dm1 >= 0.0f) corr += c1; else base += c1;
    }

    unsigned long long bal = __ballot(hot);
    if ((tid & 63) == 0 && bal) atomicOr(&s_any, 1);

    #pragma unroll
    for (int off = 32; off > 0; off >>= 1) {
        base += __shfl_down(base, off);
        corr += __shfl_down(corr, off);
    }
    int lane = tid & 63, w = tid >> 6;
    if (lane == 0) { wb[w] = base; wc[w] = corr; }
    __syncthreads();
    if (tid == 0) {
        int gid = b * SLOTB + blockIdx.x;
        pbase[gid] = wb[0] + wb[1] + wb[2] + wb[3];
        pcorr[gid] = wc[0] + wc[1] + wc[2] + wc[3];
        pflag[gid] = s_any;
    }
}

// ---------------- Kernel 2: trivial combine ----------------------------------
__global__ __launch_bounds__(256) void k_fin(
    const float* __restrict__ pbase, const float* __restrict__ pcorr,
    const int* __restrict__ pflag, float* __restrict__ out)
{
    __shared__ int npos[BD];
    __shared__ float wsum[4];
    const int tid = threadIdx.x;
    if (tid < BD) {
        int f = 0;
        for (int x = 0; x < SLOTB; ++x) f |= pflag[tid * SLOTB + x];
        npos[tid] = f;
    }
    __syncthreads();
    float s = 0.0f;
    for (int g = tid; g < NSLOT; g += 256)
        s += pbase[g] + (npos[g >> 4] ? 0.0f : pcorr[g]);
    #pragma unroll
    for (int off = 32; off > 0; off >>= 1) s += __shfl_down(s, off);
    int lane = tid & 63, w = tid >> 6;
    if (lane == 0) wsum[w] = s;
    __syncthreads();
    if (tid == 0) out[0] = (wsum[0] + wsum[1] + wsum[2] + wsum[3]) * (1.0f / (float)BD);
}

extern "C" void kernel_launch(void* const* d_in, const int* in_sizes, int n_in,
                              void* d_out, int out_size, void* d_ws, size_t ws_size,
                              hipStream_t stream) {
    (void)in_sizes; (void)n_in; (void)out_size; (void)ws_size;
    const float* outputs = (const float*)d_in[0];
    const float* targets = (const float*)d_in[1];
    const float* anchors = (const float*)d_in[2];
    float* out = (float*)d_out;

    float* pbase = (float*)d_ws;
    float* pcorr = pbase + NSLOT;
    int*   pflag = (int*)(pcorr + NSLOT);

    k_main<<<dim3(GXP + 1, BD), 256, 0, stream>>>(outputs, targets, anchors,
                                                  pbase, pcorr, pflag);
    k_fin<<<dim3(1), 256, 0, stream>>>(pbase, pcorr, pflag, out);
}